// Round 3
// baseline (146.430 us; speedup 1.0000x reference)
//
#include <hip/hip_runtime.h>
#include <hip/hip_fp16.h>

// Problem constants (fixed shapes from setup_inputs)
#define K_ROIS   512
#define BATCH    4
#define CHANNELS 1024
#define FH       50
#define FW       50
#define AH       7
#define AW       7
#define SCALE_F  0.0625f
#define CPT      8          // channels staged per block (fp16-packed, 16B/pos)

// Native clang vector type — required for __builtin_nontemporal_load
// (HIP_vector_type float4 is a class, rejected by the builtin).
typedef float vf4 __attribute__((ext_vector_type(4)));

__device__ __forceinline__ int bci(__half2 h) {
    union { __half2 h; int i; } u; u.h = h; return u.i;
}
__device__ __forceinline__ __half2 bch(unsigned int i) {
    union { unsigned int i; __half2 h; } u; u.i = i; return u.h;
}
__device__ __forceinline__ unsigned pk2(float a, float b) {
    return (unsigned)bci(__floats2half2_rn(a, b));
}
// lane l <- lane l+1 within each row of 16 (VALU pipe, zero DS cost).
__device__ __forceinline__ int dpp_sl1(int x) {
    return __builtin_amdgcn_update_dpp(0, x, 0x101 /*row_shl:1*/, 0xf, 0xf, true);
}

struct WSet { __half2 w00, w01, w10, w11; };

// Single fused kernel: per-block ROI prep (LDS) + channel-staged pooling.
// grid = BATCH * CHANNELS/CPT = 512 blocks, 512 threads.
__global__ __launch_bounds__(512, 4)
void roi_pool(const float* __restrict__ feat,
              const float* __restrict__ rois,
              float* __restrict__ out) {
    // Channel-interleaved fp16 patch: patch4[pos] = half[8] = channels c0..c0+7.
    __shared__ uint4  patch4[FH * FW];   // 40000 B
    __shared__ float4 sparams[K_ROIS];   //  8192 B  {x1,y1,bw,bh} batch-filtered
    __shared__ int    sroi[K_ROIS];      //  2048 B  original roi ids
    __shared__ int    scnt;

    const int b  = blockIdx.x & 3;
    const int c0 = (blockIdx.x >> 2) * CPT;
    const int t  = threadIdx.x;

    if (t == 0) scnt = 0;
    __syncthreads();

    // ---- in-block ROI prep: each thread owns one ROI (K_ROIS == blockDim) ----
    // Order within sroi/sparams is nondeterministic (atomic), but output
    // addresses come from the stored roi id, so results are order-invariant.
    {
        const float bf = rois[t * 5 + 0];
        const float x1 = rois[t * 5 + 1] * SCALE_F;
        const float y1 = rois[t * 5 + 2] * SCALE_F;
        const float x2 = rois[t * 5 + 3] * SCALE_F;
        const float y2 = rois[t * 5 + 4] * SCALE_F;
        if ((int)bf == b) {
            const float bw = fmaxf(x2 - x1, 0.f) * (1.f / (float)AW);
            const float bh = fmaxf(y2 - y1, 0.f) * (1.f / (float)AH);
            const int pos = atomicAdd(&scnt, 1);
            sroi[pos]    = t;
            sparams[pos] = make_float4(x1, y1, bw, bh);
        }
    }

    // ---- stage 8 channel planes, fp16 channel-interleaved (read-once: NT) ----
    {
        const vf4* pl4 = (const vf4*)(feat + ((size_t)b * CHANNELS + c0) * (FH * FW));
        for (int g = t; g < (FH * FW) / 4; g += 512) {
            vf4 v0 = __builtin_nontemporal_load(&pl4[g]);
            vf4 v1 = __builtin_nontemporal_load(&pl4[g + 1 * 625]);
            vf4 v2 = __builtin_nontemporal_load(&pl4[g + 2 * 625]);
            vf4 v3 = __builtin_nontemporal_load(&pl4[g + 3 * 625]);
            vf4 v4 = __builtin_nontemporal_load(&pl4[g + 4 * 625]);
            vf4 v5 = __builtin_nontemporal_load(&pl4[g + 5 * 625]);
            vf4 v6 = __builtin_nontemporal_load(&pl4[g + 6 * 625]);
            vf4 v7 = __builtin_nontemporal_load(&pl4[g + 7 * 625]);
            const int base = 4 * g;
            patch4[base + 0] = make_uint4(pk2(v0[0], v1[0]), pk2(v2[0], v3[0]),
                                          pk2(v4[0], v5[0]), pk2(v6[0], v7[0]));
            patch4[base + 1] = make_uint4(pk2(v0[1], v1[1]), pk2(v2[1], v3[1]),
                                          pk2(v4[1], v5[1]), pk2(v6[1], v7[1]));
            patch4[base + 2] = make_uint4(pk2(v0[2], v1[2]), pk2(v2[2], v3[2]),
                                          pk2(v4[2], v5[2]), pk2(v6[2], v7[2]));
            patch4[base + 3] = make_uint4(pk2(v0[3], v1[3]), pk2(v2[3], v3[3]),
                                          pk2(v4[3], v5[3]), pk2(v6[3], v7[3]));
        }
    }
    __syncthreads();

    const int lane = t & 63;
    const int wv   = t >> 6;            // 8 waves
    const int j = lane >> 3;
    const int i = lane & 7;
    const float jf  = (float)j;
    const float iff = (float)i;
    const bool do_out = (j < AH) && (i < AW);
    const int outoff = j * AW + i;

    const int n = scnt;                 // valid: after __syncthreads

    int rr = wv;                        // wave-uniform
    if (rr >= n) return;

    // weights carry the final *0.25 pooling factor (power of 2 — exact fold)
    auto calc = [&](float4 pp, WSet& W, int& p) {
        const float xg = fmaf(iff, pp.z, pp.x);
        const float yg = fmaf(jf, pp.w, pp.y);
        const bool valid = (yg >= 0.f) && (yg < (float)FH) &&
                           (xg >= 0.f) && (xg < (float)FW);
        const float y0f = fminf(fmaxf(floorf(yg), 0.f), (float)(FH - 2));
        const float x0f = fminf(fmaxf(floorf(xg), 0.f), (float)(FW - 2));
        const float wy = yg - y0f;
        const float wx = xg - x0f;
        const float omwy = 1.f - wy;
        const float omwx = 1.f - wx;
        float w00 = omwy * omwx;
        float w01 = omwy * wx;
        float w10 = wy * omwx;
        float w11 = wy * wx;
        if (!valid) { w00 = 0.f; w01 = 0.f; w10 = 0.f; w11 = 0.f; }
        W.w00 = __float2half2_rn(w00 * 0.25f);
        W.w01 = __float2half2_rn(w01 * 0.25f);
        W.w10 = __float2half2_rn(w10 * 0.25f);
        W.w11 = __float2half2_rn(w11 * 0.25f);
        p = (int)y0f * FW + (int)x0f;
    };

    // ---- pipeline prologue: iteration rr fully set up ----
    float4 pp = sparams[rr];
    int roi   = sroi[rr];
    WSet wc; int pc;
    calc(pp, wc, pc);
    uint4 c00 = patch4[pc];
    uint4 c01 = patch4[pc + 1];
    uint4 c10 = patch4[pc + FW];
    uint4 c11 = patch4[pc + FW + 1];

    int r1 = rr + 8;
    float4 pp1 = make_float4(0.f, 0.f, 0.f, 0.f);
    int roi1 = 0;
    if (r1 < n) { pp1 = sparams[r1]; roi1 = sroi[r1]; }

    while (true) {
        // prefetch params two iterations ahead
        const int r2 = r1 + 8;
        float4 pp2 = make_float4(0.f, 0.f, 0.f, 0.f);
        int roi2 = 0;
        if (r2 < n) { pp2 = sparams[r2]; roi2 = sroi[r2]; }

        // issue next iteration's LDS reads NOW (clamped addrs always in
        // bounds, so safe past n; result unused then)
        WSet wn; int pn;
        calc(pp1, wn, pn);
        uint4 n00 = patch4[pn];
        uint4 n01 = patch4[pn + 1];
        uint4 n10 = patch4[pn + FW];
        uint4 n11 = patch4[pn + FW + 1];

        // ---- compute current iteration ----
        // Bilinear sample, packed fp16, 2 channels per reg (v_pk_fma_f16).
        __half2 s0 = __hfma2(wc.w00, bch(c00.x), __hfma2(wc.w01, bch(c01.x),
                     __hfma2(wc.w10, bch(c10.x), __hmul2(wc.w11, bch(c11.x)))));
        __half2 s1 = __hfma2(wc.w00, bch(c00.y), __hfma2(wc.w01, bch(c01.y),
                     __hfma2(wc.w10, bch(c10.y), __hmul2(wc.w11, bch(c11.y)))));
        __half2 s2 = __hfma2(wc.w00, bch(c00.z), __hfma2(wc.w01, bch(c01.z),
                     __hfma2(wc.w10, bch(c10.z), __hmul2(wc.w11, bch(c11.z)))));
        __half2 s3 = __hfma2(wc.w00, bch(c00.w), __hfma2(wc.w01, bch(c01.w),
                     __hfma2(wc.w10, bch(c10.w), __hmul2(wc.w11, bch(c11.w)))));

        // Horizontal (+1 in i): DPP on VALU pipe, no DS traffic.
        __half2 h0 = __hadd2(s0, bch((unsigned)dpp_sl1(bci(s0))));
        __half2 h1 = __hadd2(s1, bch((unsigned)dpp_sl1(bci(s1))));
        __half2 h2 = __hadd2(s2, bch((unsigned)dpp_sl1(bci(s2))));
        __half2 h3 = __hadd2(s3, bch((unsigned)dpp_sl1(bci(s3))));

        // Vertical (+1 in j = lane+8): 4 bpermutes cover 8 channels.
        __half2 t0 = __hadd2(h0, bch((unsigned)__shfl_down(bci(h0), 8)));
        __half2 t1 = __hadd2(h1, bch((unsigned)__shfl_down(bci(h1), 8)));
        __half2 t2 = __hadd2(h2, bch((unsigned)__shfl_down(bci(h2), 8)));
        __half2 t3 = __hadd2(h3, bch((unsigned)__shfl_down(bci(h3), 8)));

        if (do_out) {
            const size_t ob = (size_t)roi * (CHANNELS * AH * AW)
                            + (size_t)c0 * (AH * AW) + outoff;
            float2 f0 = __half22float2(t0);
            float2 f1 = __half22float2(t1);
            float2 f2 = __half22float2(t2);
            float2 f3 = __half22float2(t3);
            __builtin_nontemporal_store(f0.x, &out[ob + 0 * AH * AW]);
            __builtin_nontemporal_store(f0.y, &out[ob + 1 * AH * AW]);
            __builtin_nontemporal_store(f1.x, &out[ob + 2 * AH * AW]);
            __builtin_nontemporal_store(f1.y, &out[ob + 3 * AH * AW]);
            __builtin_nontemporal_store(f2.x, &out[ob + 4 * AH * AW]);
            __builtin_nontemporal_store(f2.y, &out[ob + 5 * AH * AW]);
            __builtin_nontemporal_store(f3.x, &out[ob + 6 * AH * AW]);
            __builtin_nontemporal_store(f3.y, &out[ob + 7 * AH * AW]);
        }

        // ---- rotate pipeline state ----
        rr = r1;
        if (rr >= n) break;
        roi = roi1;
        wc = wn;
        c00 = n00; c01 = n01; c10 = n10; c11 = n11;
        r1 = r2; pp1 = pp2; roi1 = roi2;
    }
}

extern "C" void kernel_launch(void* const* d_in, const int* in_sizes, int n_in,
                              void* d_out, int out_size, void* d_ws, size_t ws_size,
                              hipStream_t stream) {
    const float* feat = (const float*)d_in[0];
    const float* rois = (const float*)d_in[1];
    float* out = (float*)d_out;
    (void)d_ws; (void)ws_size;

    roi_pool<<<BATCH * (CHANNELS / CPT), 512, 0, stream>>>(feat, rois, out);
}

// Round 5
// 139.502 us; speedup vs baseline: 1.0497x; 1.0497x over previous
//
#include <hip/hip_runtime.h>
#include <hip/hip_fp16.h>

// Problem constants (fixed shapes from setup_inputs)
#define K_ROIS   512
#define BATCH    4
#define CHANNELS 1024
#define FH       50
#define FW       50
#define AH       7
#define AW       7
#define SCALE_F  0.0625f
#define CPT      8          // channels staged per block (fp16-packed, 16B/pos)

__device__ __forceinline__ int bci(__half2 h) {
    union { __half2 h; int i; } u; u.h = h; return u.i;
}
__device__ __forceinline__ __half2 bch(unsigned int i) {
    union { unsigned int i; __half2 h; } u; u.i = i; return u.h;
}
__device__ __forceinline__ unsigned pk2(float a, float b) {
    return (unsigned)bci(__floats2half2_rn(a, b));
}
// lane l <- lane l+1 within each row of 16 (VALU pipe, zero DS cost).
__device__ __forceinline__ int dpp_sl1(int x) {
    return __builtin_amdgcn_update_dpp(0, x, 0x101 /*row_shl:1*/, 0xf, 0xf, true);
}

// Single fused kernel: per-block ROI prep (LDS) + channel-staged pooling.
// grid = BATCH * CHANNELS/CPT = 512 blocks, 512 threads.
// NOTE (round-3 post-mortem): measured window is ~128us of harness poison
// fills + ~15us of this kernel. Features/output are L3-hot in the bench
// loop -> do NOT use nontemporal hints (they bypass L3 and cost ~4us).
// Deep LDS-read software pipelining regressed (VGPR pressure, LDS latency
// was never the bottleneck) -> params-prefetch only.
__global__ __launch_bounds__(512)
void roi_pool(const float* __restrict__ feat,
              const float* __restrict__ rois,
              float* __restrict__ out) {
    // Channel-interleaved fp16 patch: patch4[pos] = half[8] = channels c0..c0+7.
    __shared__ uint4  patch4[FH * FW];   // 40000 B
    __shared__ float4 sparams[K_ROIS];   //  8192 B  {x1,y1,bw,bh} batch-filtered
    __shared__ int    sroi[K_ROIS];      //  2048 B  original roi ids
    __shared__ int    scnt;

    const int b  = blockIdx.x & 3;
    const int c0 = (blockIdx.x >> 2) * CPT;
    const int t  = threadIdx.x;

    if (t == 0) scnt = 0;
    __syncthreads();

    // ---- in-block ROI prep: each thread owns one ROI (K_ROIS == blockDim) ----
    // Order within sroi/sparams is nondeterministic (atomic), but output
    // addresses come from the stored roi id, so results are order-invariant.
    {
        const float bf = rois[t * 5 + 0];
        const float x1 = rois[t * 5 + 1] * SCALE_F;
        const float y1 = rois[t * 5 + 2] * SCALE_F;
        const float x2 = rois[t * 5 + 3] * SCALE_F;
        const float y2 = rois[t * 5 + 4] * SCALE_F;
        if ((int)bf == b) {
            const float bw = fmaxf(x2 - x1, 0.f) * (1.f / (float)AW);
            const float bh = fmaxf(y2 - y1, 0.f) * (1.f / (float)AH);
            const int pos = atomicAdd(&scnt, 1);
            sroi[pos]    = t;
            sparams[pos] = make_float4(x1, y1, bw, bh);
        }
    }

    // ---- stage 8 channel planes, fp16 channel-interleaved ----
    {
        const float4* pl4 = (const float4*)(feat + ((size_t)b * CHANNELS + c0) * (FH * FW));
        for (int g = t; g < (FH * FW) / 4; g += 512) {
            float4 v0 = pl4[g];
            float4 v1 = pl4[g + 1 * 625];
            float4 v2 = pl4[g + 2 * 625];
            float4 v3 = pl4[g + 3 * 625];
            float4 v4 = pl4[g + 4 * 625];
            float4 v5 = pl4[g + 5 * 625];
            float4 v6 = pl4[g + 6 * 625];
            float4 v7 = pl4[g + 7 * 625];
            const int base = 4 * g;
            patch4[base + 0] = make_uint4(pk2(v0.x, v1.x), pk2(v2.x, v3.x),
                                          pk2(v4.x, v5.x), pk2(v6.x, v7.x));
            patch4[base + 1] = make_uint4(pk2(v0.y, v1.y), pk2(v2.y, v3.y),
                                          pk2(v4.y, v5.y), pk2(v6.y, v7.y));
            patch4[base + 2] = make_uint4(pk2(v0.z, v1.z), pk2(v2.z, v3.z),
                                          pk2(v4.z, v5.z), pk2(v6.z, v7.z));
            patch4[base + 3] = make_uint4(pk2(v0.w, v1.w), pk2(v2.w, v3.w),
                                          pk2(v4.w, v5.w), pk2(v6.w, v7.w));
        }
    }
    __syncthreads();

    const int lane = t & 63;
    const int wv   = t >> 6;            // 8 waves
    const int j = lane >> 3;
    const int i = lane & 7;
    const float jf  = (float)j;
    const float iff = (float)i;
    const bool do_out = (j < AH) && (i < AW);
    const int outoff = j * AW + i;

    const int n = scnt;                 // valid: after __syncthreads

    int rr = wv;                        // wave-uniform
    float4 pp = make_float4(0.f, 0.f, 0.f, 0.f);
    int roi = 0;
    if (rr < n) { pp = sparams[rr]; roi = sroi[rr]; }

    while (rr < n) {
        // Prefetch next iteration's params (independent LDS loads).
        const int rn = rr + 8;
        float4 ppn = pp;
        int roin = roi;
        if (rn < n) { ppn = sparams[rn]; roin = sroi[rn]; }

        const float xg = fmaf(iff, pp.z, pp.x);
        const float yg = fmaf(jf, pp.w, pp.y);
        const bool valid = (yg >= 0.f) && (yg < (float)FH) &&
                           (xg >= 0.f) && (xg < (float)FW);
        const float y0f = fminf(fmaxf(floorf(yg), 0.f), (float)(FH - 2));
        const float x0f = fminf(fmaxf(floorf(xg), 0.f), (float)(FW - 2));
        const float wy = yg - y0f;
        const float wx = xg - x0f;
        const float omwy = 1.f - wy;
        const float omwx = 1.f - wx;
        float w00 = omwy * omwx;
        float w01 = omwy * wx;
        float w10 = wy * omwx;
        float w11 = wy * wx;
        if (!valid) { w00 = 0.f; w01 = 0.f; w10 = 0.f; w11 = 0.f; }
        const int p = (int)y0f * FW + (int)x0f;

        const uint4 c00 = patch4[p];
        const uint4 c01 = patch4[p + 1];
        const uint4 c10 = patch4[p + FW];
        const uint4 c11 = patch4[p + FW + 1];

        // final *0.25 pooling factor folded into weights (pow2 — exact)
        const __half2 W00 = __float2half2_rn(w00 * 0.25f);
        const __half2 W01 = __float2half2_rn(w01 * 0.25f);
        const __half2 W10 = __float2half2_rn(w10 * 0.25f);
        const __half2 W11 = __float2half2_rn(w11 * 0.25f);

        // Bilinear sample, packed fp16, 2 channels per reg (v_pk_fma_f16).
        __half2 s0 = __hfma2(W00, bch(c00.x), __hfma2(W01, bch(c01.x),
                     __hfma2(W10, bch(c10.x), __hmul2(W11, bch(c11.x)))));
        __half2 s1 = __hfma2(W00, bch(c00.y), __hfma2(W01, bch(c01.y),
                     __hfma2(W10, bch(c10.y), __hmul2(W11, bch(c11.y)))));
        __half2 s2 = __hfma2(W00, bch(c00.z), __hfma2(W01, bch(c01.z),
                     __hfma2(W10, bch(c10.z), __hmul2(W11, bch(c11.z)))));
        __half2 s3 = __hfma2(W00, bch(c00.w), __hfma2(W01, bch(c01.w),
                     __hfma2(W10, bch(c10.w), __hmul2(W11, bch(c11.w)))));

        // Horizontal (+1 in i): DPP on VALU pipe, no DS traffic.
        __half2 h0 = __hadd2(s0, bch((unsigned)dpp_sl1(bci(s0))));
        __half2 h1 = __hadd2(s1, bch((unsigned)dpp_sl1(bci(s1))));
        __half2 h2 = __hadd2(s2, bch((unsigned)dpp_sl1(bci(s2))));
        __half2 h3 = __hadd2(s3, bch((unsigned)dpp_sl1(bci(s3))));

        // Vertical (+1 in j = lane+8): 4 bpermutes cover 8 channels.
        __half2 t0 = __hadd2(h0, bch((unsigned)__shfl_down(bci(h0), 8)));
        __half2 t1 = __hadd2(h1, bch((unsigned)__shfl_down(bci(h1), 8)));
        __half2 t2 = __hadd2(h2, bch((unsigned)__shfl_down(bci(h2), 8)));
        __half2 t3 = __hadd2(h3, bch((unsigned)__shfl_down(bci(h3), 8)));

        if (do_out) {
            const size_t ob = (size_t)roi * (CHANNELS * AH * AW)
                            + (size_t)c0 * (AH * AW) + outoff;
            float2 f0 = __half22float2(t0);
            float2 f1 = __half22float2(t1);
            float2 f2 = __half22float2(t2);
            float2 f3 = __half22float2(t3);
            out[ob + 0 * AH * AW] = f0.x;
            out[ob + 1 * AH * AW] = f0.y;
            out[ob + 2 * AH * AW] = f1.x;
            out[ob + 3 * AH * AW] = f1.y;
            out[ob + 4 * AH * AW] = f2.x;
            out[ob + 5 * AH * AW] = f2.y;
            out[ob + 6 * AH * AW] = f3.x;
            out[ob + 7 * AH * AW] = f3.y;
        }

        pp = ppn; roi = roin; rr = rn;
    }
}

extern "C" void kernel_launch(void* const* d_in, const int* in_sizes, int n_in,
                              void* d_out, int out_size, void* d_ws, size_t ws_size,
                              hipStream_t stream) {
    const float* feat = (const float*)d_in[0];
    const float* rois = (const float*)d_in[1];
    float* out = (float*)d_out;
    (void)d_ws; (void)ws_size;

    roi_pool<<<BATCH * (CHANNELS / CPT), 512, 0, stream>>>(feat, rois, out);
}